// Round 11
// baseline (198.807 us; speedup 1.0000x reference)
//
#include <hip/hip_runtime.h>
#include <stdint.h>

#define D 128
#define EPB 4096   // edges per histogram/scatter block (R0/R8-proven; sb = ceil(C*B1n/256) must be <= 256)
#define CSZ 128    // nodes per cluster (cluster = dst >> 7)

typedef __bf16 bf16x8 __attribute__((ext_vector_type(8)));
typedef float f32x4 __attribute__((ext_vector_type(4)));

__device__ inline float bf2f(unsigned short u) {
    return __uint_as_float((unsigned)u << 16);
}
__device__ inline unsigned short f2bf(float f) {
    unsigned u = __float_as_uint(f);
    return (unsigned short)((u + 0x7FFF + ((u >> 16) & 1)) >> 16);  // RNE
}

struct Params {
    const float* x; const int* ei; const float* ew;
    const float* W1; const float* b1; const float* W2; const float* b2;
    float* out;
    int N, E, C, B1n, total, gb, gb2, hb16, sb;
    unsigned short *Wt1, *Wt2;
    unsigned int* bh; int* ebase; int* bsums;
    float* dinv; int* cnt; int* rowstart;
    int2* brec; int2* erec;
    unsigned short *Hbuf, *Abuf;
};

// ================= phase bodies (R0/R8-verified mechanism) =================

__device__ inline void dev_prep(int which, const Params& p) {
    const float* W = (which == 0) ? p.W1 : p.W2;
    unsigned short* Wt = (which == 0) ? p.Wt1 : p.Wt2;
    for (int i = threadIdx.x; i < 2048; i += 256) {
        int nn = i >> 4;
        int kc = (i & 15) << 3;
        ushort4 o0, o1;
        o0.x = f2bf(W[(kc + 0) * 128 + nn]); o0.y = f2bf(W[(kc + 1) * 128 + nn]);
        o0.z = f2bf(W[(kc + 2) * 128 + nn]); o0.w = f2bf(W[(kc + 3) * 128 + nn]);
        o1.x = f2bf(W[(kc + 4) * 128 + nn]); o1.y = f2bf(W[(kc + 5) * 128 + nn]);
        o1.z = f2bf(W[(kc + 6) * 128 + nn]); o1.w = f2bf(W[(kc + 7) * 128 + nn]);
        *(ushort4*)(Wt + nn * 128 + kc) = o0;
        *(ushort4*)(Wt + nn * 128 + kc + 4) = o1;
    }
}

__device__ inline void dev_hist(int b, const Params& p, unsigned int* hist) {
    for (int i = threadIdx.x; i < p.C; i += 256) hist[i] = 0;
    __syncthreads();
    const int base = b * EPB + threadIdx.x;
#pragma unroll
    for (int k = 0; k < EPB / 256; ++k) {
        int e = base + k * 256;
        if (e < p.E) atomicAdd(&hist[((unsigned)p.ei[p.E + e]) >> 7], 1u);
    }
    __syncthreads();
    for (int i = threadIdx.x; i < p.C; i += 256) p.bh[(size_t)b * p.C + i] = hist[i];
}

__device__ inline void dev_scanA(int blk, const Params& p, int* tmp) {
    const int tid = threadIdx.x;
    const int i = blk * 256 + tid;
    int v = 0;
    if (i < p.total) {
        int c = i / p.B1n;
        int b = i - c * p.B1n;
        v = (int)p.bh[(size_t)b * p.C + c];
    }
    tmp[tid] = v;
    __syncthreads();
    for (int off = 1; off < 256; off <<= 1) {
        int t = (tid >= off) ? tmp[tid - off] : 0;
        __syncthreads();
        tmp[tid] += t;
        __syncthreads();
    }
    if (i < p.total) p.ebase[i] = tmp[tid] - v;    // block-local exclusive prefix
    if (tid == 255) p.bsums[blk] = tmp[255];
}

// block-local exclusive prefix of bsums[0..sb) into LDS (replaces the scanB kernel).
// Requires sb <= 256 (sb = 225 for N=50000, E=600000, EPB=4096).
__device__ inline void block_pref(const Params& p, int* spref) {
    const int tid = threadIdx.x;
    int v = (tid < p.sb) ? p.bsums[tid] : 0;
    spref[tid] = v;
    __syncthreads();
    for (int off = 1; off < 256; off <<= 1) {
        int t = (tid >= off) ? spref[tid - off] : 0;
        __syncthreads();
        spref[tid] += t;
        __syncthreads();
    }
    int incl = spref[tid];
    __syncthreads();
    spref[tid] = incl - v;   // exclusive
    __syncthreads();
}

__device__ inline void dev_scat(int b, const Params& p, unsigned int* cur, const int* spref) {
    for (int i = threadIdx.x; i < p.C; i += 256) cur[i] = 0;
    __syncthreads();
    const int base = b * EPB + threadIdx.x;
#pragma unroll
    for (int k = 0; k < EPB / 256; ++k) {
        int e = base + k * 256;
        if (e < p.E) {
            int s = p.ei[e];
            unsigned d = (unsigned)p.ei[p.E + e];
            float w = p.ew[e];
            int c = d >> 7;
            unsigned r = atomicAdd(&cur[c], 1u);
            int idx = c * p.B1n + b;
            int pos = p.ebase[idx] + spref[idx >> 8] + (int)r;
            p.brec[pos] = make_int2((int)((d << 16) | (unsigned)s), __float_as_int(w));
        }
    }
}

__device__ inline void dev_cbuild(int c, const Params& p, unsigned int* a, const int* spref) {
    unsigned int* hcnt = a;
    unsigned int* hdeg = a + CSZ;
    unsigned int* lsc  = a + 2 * CSZ;
    unsigned int* curs = a + 3 * CSZ;
    const int tid = threadIdx.x;
    const int i0 = c * p.B1n;
    const int cs = p.ebase[i0] + spref[i0 >> 8];
    int ce;
    if (c + 1 < p.C) {
        const int i1 = (c + 1) * p.B1n;
        ce = p.ebase[i1] + spref[i1 >> 8];
    } else {
        ce = p.E;
    }
    if (tid < CSZ) { hcnt[tid] = 0; hdeg[tid] = 0; }
    __syncthreads();
    for (int i = cs + tid; i < ce; i += 256) {
        int2 r = p.brec[i];
        int local = (int)(((unsigned)r.x) >> 16) & (CSZ - 1);
        atomicAdd(&hcnt[local], 1u);
        atomicAdd(&hdeg[local], (unsigned)(__int_as_float(r.y) * 16777216.0f));
    }
    __syncthreads();
    if (tid < CSZ) lsc[tid] = hcnt[tid];
    __syncthreads();
    for (int off = 1; off < CSZ; off <<= 1) {
        unsigned t = (tid < CSZ && tid >= off) ? lsc[tid - off] : 0u;
        __syncthreads();
        if (tid < CSZ) lsc[tid] += t;
        __syncthreads();
    }
    if (tid < CSZ) {
        unsigned excl = lsc[tid] - hcnt[tid];
        curs[tid] = excl;
        int node = c * CSZ + tid;
        if (node < p.N) {
            p.rowstart[node] = cs + (int)excl;
            p.cnt[node] = (int)hcnt[tid];
            float deg = 1.0f + (float)hdeg[tid] * (1.0f / 16777216.0f);
            p.dinv[node] = rsqrtf(deg);
        }
    }
    __syncthreads();
    for (int i = cs + tid; i < ce; i += 256) {
        int2 r = p.brec[i];
        int local = (int)(((unsigned)r.x) >> 16) & (CSZ - 1);
        unsigned rk = atomicAdd(&curs[local], 1u);
        p.erec[cs + (int)rk] = make_int2(r.x & 0xFFFF, r.y);   // (src, ew)
    }
}

// ---------------- MFMA GEMM body (R0-verified, verbatim): GEMM1 ----------------
template <bool IN_BF16>
__device__ inline void mfma_body(unsigned short* sE,
                                 const void* __restrict__ Xv,
                                 const unsigned short* __restrict__ Wt,
                                 unsigned short* __restrict__ H, int n, int blk) {
    const int tid = threadIdx.x;
    const int row0 = blk * 64;
    const int lane = tid & 63;
    const int wv = tid >> 6;
    const int qm = lane & 15;
    const int quad = lane >> 4;

    const int arow = row0 + wv * 16 + qm;
    const int ar = (arow < n) ? arow : (n - 1);

    f32x4 acc[8];
#pragma unroll
    for (int i = 0; i < 8; ++i) acc[i] = (f32x4){0.f, 0.f, 0.f, 0.f};

#pragma unroll
    for (int kb = 0; kb < 4; ++kb) {
        const int koff = kb * 32 + quad * 8;
        bf16x8 a;
        if (IN_BF16) {
            a = *(const bf16x8*)((const unsigned short*)Xv + (size_t)ar * 128 + koff);
        } else {
            const float* Xf = (const float*)Xv + (size_t)ar * 128 + koff;
            float4 v0 = *(const float4*)(Xf);
            float4 v1 = *(const float4*)(Xf + 4);
            union { bf16x8 v; ushort4 u[2]; } cv;
            cv.u[0].x = f2bf(v0.x); cv.u[0].y = f2bf(v0.y);
            cv.u[0].z = f2bf(v0.z); cv.u[0].w = f2bf(v0.w);
            cv.u[1].x = f2bf(v1.x); cv.u[1].y = f2bf(v1.y);
            cv.u[1].z = f2bf(v1.z); cv.u[1].w = f2bf(v1.w);
            a = cv.v;
        }
#pragma unroll
        for (int n0 = 0; n0 < 8; ++n0) {
            bf16x8 b = *(const bf16x8*)(Wt + (n0 * 16 + qm) * 128 + koff);
            acc[n0] = __builtin_amdgcn_mfma_f32_16x16x32_bf16(a, b, acc[n0], 0, 0, 0);
        }
    }

#pragma unroll
    for (int n0 = 0; n0 < 8; ++n0)
#pragma unroll
        for (int r = 0; r < 4; ++r)
            sE[(wv * 16 + quad * 4 + r) * 136 + n0 * 16 + qm] = f2bf(acc[n0][r]);
    __syncthreads();

    const int row_in = lane >> 2;
    const int c0 = (lane & 3) * 4;
    const int grow = row0 + wv * 16 + row_in;
    if (grow < n) {
#pragma unroll
        for (int j = 0; j < 4; ++j)
            *(int4*)(H + (size_t)grow * 128 + (c0 + j) * 8) =
                *(const int4*)(&sE[(wv * 16 + row_in) * 136 + (c0 + j) * 8]);
    }
}

// ---------------- gather layer-1, 16 lanes/node, int4 row loads (R8-verified, 4-deep) ----------------
__device__ inline void gather1_node16(const Params& p, unsigned short* dst, int node, int lane) {
    const int4* __restrict__ H16 = (const int4*)p.Hbuf;   // 16 int4 per 128-col bf16 row
    union U8 { int4 v; unsigned short u[8]; };
    if (node < p.N) {
        const int start = p.rowstart[node];
        const int m = p.cnt[node];
        const float di = p.dinv[node];
        U8 s; s.v = H16[(size_t)node * 16 + lane];
        float acc[8];
#pragma unroll
        for (int q = 0; q < 8; ++q) acc[q] = di * bf2f(s.u[q]);

        const int2* __restrict__ er = p.erec + start;
        int j = 0;
        for (; j + 4 <= m; j += 4) {
            int2 e0 = er[j], e1 = er[j + 1], e2 = er[j + 2], e3 = er[j + 3];
            U8 v0, v1, v2, v3;
            v0.v = H16[(size_t)e0.x * 16 + lane];
            v1.v = H16[(size_t)e1.x * 16 + lane];
            v2.v = H16[(size_t)e2.x * 16 + lane];
            v3.v = H16[(size_t)e3.x * 16 + lane];
            float w0 = p.dinv[e0.x] * __int_as_float(e0.y);
            float w1 = p.dinv[e1.x] * __int_as_float(e1.y);
            float w2 = p.dinv[e2.x] * __int_as_float(e2.y);
            float w3 = p.dinv[e3.x] * __int_as_float(e3.y);
#pragma unroll
            for (int q = 0; q < 8; ++q)
                acc[q] += w0 * bf2f(v0.u[q]) + w1 * bf2f(v1.u[q]) +
                          w2 * bf2f(v2.u[q]) + w3 * bf2f(v3.u[q]);
        }
        for (; j < m; ++j) {
            int2 e0 = er[j];
            U8 v0; v0.v = H16[(size_t)e0.x * 16 + lane];
            float w0 = p.dinv[e0.x] * __int_as_float(e0.y);
#pragma unroll
            for (int q = 0; q < 8; ++q) acc[q] += w0 * bf2f(v0.u[q]);
        }
        const float4 b0 = *(const float4*)(p.b1 + lane * 8);
        const float4 b1v = *(const float4*)(p.b1 + lane * 8 + 4);
        const float bb[8] = {b0.x, b0.y, b0.z, b0.w, b1v.x, b1v.y, b1v.z, b1v.w};
        U8 o;
#pragma unroll
        for (int q = 0; q < 8; ++q) o.u[q] = f2bf(fmaxf(bb[q] + di * acc[q], 0.f));
        *(int4*)dst = o.v;
    } else {
        *(int4*)dst = (int4){0, 0, 0, 0};
    }
}

// ---------------- gather layer 2, 16 lanes/node, int4 row loads (R8-verified, 4-deep) ----------------
// H2s rows pre-scaled by dinv (folded into fused GEMM2 epilogue) -> no per-edge dinv load.
__device__ inline void gather2_body16(const Params& p, const int4* __restrict__ H16,
                                      const float* __restrict__ bias,
                                      float4* __restrict__ OUT, int g) {
    const int lane = threadIdx.x & 15;
    const int node = g * 16 + (threadIdx.x >> 4);
    if (node >= p.N) return;
    const int start = p.rowstart[node];
    const int m = p.cnt[node];
    const float di = p.dinv[node];

    union U8 { int4 v; unsigned short u[8]; };
    U8 s; s.v = H16[(size_t)node * 16 + lane];
    float acc[8];
#pragma unroll
    for (int q = 0; q < 8; ++q) acc[q] = bf2f(s.u[q]);

    const int2* __restrict__ er = p.erec + start;
    int j = 0;
    for (; j + 4 <= m; j += 4) {
        int2 e0 = er[j], e1 = er[j + 1], e2 = er[j + 2], e3 = er[j + 3];
        U8 v0, v1, v2, v3;
        v0.v = H16[(size_t)e0.x * 16 + lane];
        v1.v = H16[(size_t)e1.x * 16 + lane];
        v2.v = H16[(size_t)e2.x * 16 + lane];
        v3.v = H16[(size_t)e3.x * 16 + lane];
        float w0 = __int_as_float(e0.y), w1 = __int_as_float(e1.y);
        float w2 = __int_as_float(e2.y), w3 = __int_as_float(e3.y);
#pragma unroll
        for (int q = 0; q < 8; ++q)
            acc[q] += w0 * bf2f(v0.u[q]) + w1 * bf2f(v1.u[q]) +
                      w2 * bf2f(v2.u[q]) + w3 * bf2f(v3.u[q]);
    }
    for (; j < m; ++j) {
        int2 e0 = er[j];
        U8 v0; v0.v = H16[(size_t)e0.x * 16 + lane];
        float w0 = __int_as_float(e0.y);
#pragma unroll
        for (int q = 0; q < 8; ++q) acc[q] += w0 * bf2f(v0.u[q]);
    }

    const float4 b0 = *(const float4*)(bias + lane * 8);
    const float4 b1v = *(const float4*)(bias + lane * 8 + 4);
    float4 f0, f1;
    f0.x = b0.x + di * acc[0]; f0.y = b0.y + di * acc[1];
    f0.z = b0.z + di * acc[2]; f0.w = b0.w + di * acc[3];
    f1.x = b1v.x + di * acc[4]; f1.y = b1v.y + di * acc[5];
    f1.z = b1v.z + di * acc[6]; f1.w = b1v.w + di * acc[7];
    OUT[(size_t)node * 32 + lane * 2] = f0;
    OUT[(size_t)node * 32 + lane * 2 + 1] = f1;
}

// ================= 6-kernel pipeline =================
__global__ __launch_bounds__(256, 4) void k_f0(Params p) {   // prep + hist
    __shared__ __align__(16) unsigned int hist[512];
    if (blockIdx.x < 2) dev_prep(blockIdx.x, p);
    else dev_hist(blockIdx.x - 2, p, hist);
}
__global__ __launch_bounds__(256, 4) void k_f1(Params p) {   // GEMM1 + scanA
    __shared__ __align__(16) char arena[64 * 136 * 2];
    if ((int)blockIdx.x < p.gb) mfma_body<false>((unsigned short*)arena, (const void*)p.x, p.Wt1, p.Hbuf, p.N, blockIdx.x);
    else dev_scanA(blockIdx.x - p.gb, p, (int*)arena);
}
__global__ __launch_bounds__(256) void k_f3(Params p) {      // scatter -> brec (local bsums prefix)
    __shared__ unsigned int cur[512];
    __shared__ int spref[256];
    block_pref(p, spref);
    dev_scat(blockIdx.x, p, cur, spref);
}
__global__ __launch_bounds__(256) void k_f4(Params p) {      // CSR build (local bsums prefix)
    __shared__ unsigned int a[4 * CSZ];
    __shared__ int spref[256];
    block_pref(p, spref);
    dev_cbuild(blockIdx.x, p, a, spref);
}
// fused gather1 + GEMM2, 32-row tile, 16-lane 4-deep gather + dinv-fold epilogue (R8-verified)
__global__ __launch_bounds__(256, 4) void k_g5(Params p) {
    __shared__ __align__(16) unsigned short sA[32 * 136];
    __shared__ __align__(16) unsigned short sE[32 * 136];
    const int row0 = blockIdx.x * 32;
    const int tid = threadIdx.x;

    // gather 32 nodes: 16 lanes/node, 16 nodes/pass, 2 passes
    const int lane16 = tid & 15;
    const int grp16 = tid >> 4;   // 0..15
#pragma unroll
    for (int pass = 0; pass < 2; ++pass) {
        const int local = pass * 16 + grp16;
        gather1_node16(p, sA + local * 136 + lane16 * 8, row0 + local, lane16);
    }
    __syncthreads();

    const int lane = tid & 63;
    const int wv = tid >> 6;        // 0..3
    const int qm = lane & 15;
    const int quad = lane >> 4;
    const int rh = wv & 1;          // row half (16 rows)
    const int ch = wv >> 1;         // col half (64 cols)

    f32x4 acc[4];
#pragma unroll
    for (int i = 0; i < 4; ++i) acc[i] = (f32x4){0.f, 0.f, 0.f, 0.f};

#pragma unroll
    for (int kb = 0; kb < 4; ++kb) {
        const int koff = kb * 32 + quad * 8;
        bf16x8 a = *(const bf16x8*)(sA + (rh * 16 + qm) * 136 + koff);
#pragma unroll
        for (int n0 = 0; n0 < 4; ++n0) {
            bf16x8 b = *(const bf16x8*)(p.Wt2 + ((ch * 4 + n0) * 16 + qm) * 128 + koff);
            acc[n0] = __builtin_amdgcn_mfma_f32_16x16x32_bf16(a, b, acc[n0], 0, 0, 0);
        }
    }

    // per-C-row dinv (fold into H2s, fp32 before the single bf16 rounding)
    const int crow = rh * 16 + quad * 4;
    float di[4];
#pragma unroll
    for (int r = 0; r < 4; ++r) {
        int rr = row0 + crow + r;
        int rc = (rr < p.N) ? rr : (p.N - 1);
        di[r] = p.dinv[rc];
    }

#pragma unroll
    for (int n0 = 0; n0 < 4; ++n0)
#pragma unroll
        for (int r = 0; r < 4; ++r)
            sE[(crow + r) * 136 + ch * 64 + n0 * 16 + qm] = f2bf(acc[n0][r] * di[r]);
    __syncthreads();

    // write 32 rows x 128 cols: each thread 2 int4 chunks
    const int row_in = tid >> 3;          // 0..31
    const int c0 = (tid & 7) * 2;         // int4-chunk pair
    const int grow = row0 + row_in;
    if (grow < p.N) {
        *(int4*)(p.Abuf + (size_t)grow * 128 + (c0 + 0) * 8) =
            *(const int4*)(&sE[row_in * 136 + (c0 + 0) * 8]);
        *(int4*)(p.Abuf + (size_t)grow * 128 + (c0 + 1) * 8) =
            *(const int4*)(&sE[row_in * 136 + (c0 + 1) * 8]);
    }
}
__global__ __launch_bounds__(256) void k_g6(Params p) {      // gather2 -> out fp32
    gather2_body16(p, (const int4*)p.Abuf, p.b2, (float4*)p.out, blockIdx.x);
}

extern "C" void kernel_launch(void* const* d_in, const int* in_sizes, int n_in,
                              void* d_out, int out_size, void* d_ws, size_t ws_size,
                              hipStream_t stream) {
    Params p;
    p.x  = (const float*)d_in[0];
    p.ei = (const int*)d_in[1];
    p.ew = (const float*)d_in[2];
    p.W1 = (const float*)d_in[3];
    p.b1 = (const float*)d_in[4];
    p.W2 = (const float*)d_in[5];
    p.b2 = (const float*)d_in[6];
    p.out = (float*)d_out;

    p.N = in_sizes[0] / D;
    p.E = in_sizes[2];
    p.C = (p.N + CSZ - 1) / CSZ;
    p.B1n = (p.E + EPB - 1) / EPB;
    p.total = p.C * p.B1n;
    p.sb = (p.total + 255) / 256;     // must be <= 256 for block_pref (225 here)
    p.gb = (p.N + 63) / 64;
    p.gb2 = (p.N + 31) / 32;
    p.hb16 = (p.N + 15) / 16;

    char* w = (char*)d_ws;
    auto alloc = [&](size_t bytes) {
        void* r = (void*)w;
        w += (bytes + 255) & ~(size_t)255;
        return r;
    };
    p.bh       = (unsigned int*)alloc((size_t)p.total * 4);
    p.ebase    = (int*)alloc((size_t)p.total * 4);
    p.bsums    = (int*)alloc((size_t)(p.sb + 1) * 4);
    p.dinv     = (float*)alloc((size_t)p.N * 4);
    p.cnt      = (int*)alloc((size_t)p.N * 4);
    p.rowstart = (int*)alloc((size_t)p.N * 4);
    p.brec     = (int2*)alloc((size_t)p.E * 8);
    p.erec     = (int2*)alloc((size_t)p.E * 8);
    p.Hbuf     = (unsigned short*)alloc((size_t)p.N * D * 2);
    p.Abuf     = (unsigned short*)alloc((size_t)p.N * D * 2);
    p.Wt1      = (unsigned short*)alloc(128 * 128 * 2);
    p.Wt2      = (unsigned short*)alloc(128 * 128 * 2);

    k_f0<<<2 + p.B1n, 256, 0, stream>>>(p);
    k_f1<<<p.gb + p.sb, 256, 0, stream>>>(p);
    k_f3<<<p.B1n, 256, 0, stream>>>(p);
    k_f4<<<p.C, 256, 0, stream>>>(p);
    k_g5<<<p.gb2, 256, 0, stream>>>(p);
    k_g6<<<p.hb16, 256, 0, stream>>>(p);
}

// Round 12
// 194.645 us; speedup vs baseline: 1.0214x; 1.0214x over previous
//
#include <hip/hip_runtime.h>
#include <stdint.h>

#define D 128
#define EPB 4096   // edges per histogram/scatter block (R0/R8-proven; sb must be <= 256)
#define CSZ 128    // nodes per cluster (cluster = dst >> 7)

typedef __bf16 bf16x8 __attribute__((ext_vector_type(8)));
typedef float f32x4 __attribute__((ext_vector_type(4)));

__device__ inline float bf2f(unsigned short u) {
    return __uint_as_float((unsigned)u << 16);
}
__device__ inline unsigned short f2bf(float f) {
    unsigned u = __float_as_uint(f);
    return (unsigned short)((u + 0x7FFF + ((u >> 16) & 1)) >> 16);  // RNE
}

struct Params {
    const float* x; const int* ei; const float* ew;
    const float* W1; const float* b1; const float* W2; const float* b2;
    float* out;
    int N, E, C, B1n, total, gb, gb2, hb16, sb, g1, g2, g3;
    unsigned short *Wt1, *Wt2;
    unsigned int* bh; int* ebase; int* bsums;
    float* dinv; int* cnt; int* rowstart;
    int2* brec; int2* erec;
    unsigned short *Hbuf, *Abuf;
};

// ================= phase bodies (R0/R8/R11-verified mechanism) =================

__device__ inline void dev_prep(int which, const Params& p) {
    const float* W = (which == 0) ? p.W1 : p.W2;
    unsigned short* Wt = (which == 0) ? p.Wt1 : p.Wt2;
    for (int i = threadIdx.x; i < 2048; i += 256) {
        int nn = i >> 4;
        int kc = (i & 15) << 3;
        ushort4 o0, o1;
        o0.x = f2bf(W[(kc + 0) * 128 + nn]); o0.y = f2bf(W[(kc + 1) * 128 + nn]);
        o0.z = f2bf(W[(kc + 2) * 128 + nn]); o0.w = f2bf(W[(kc + 3) * 128 + nn]);
        o1.x = f2bf(W[(kc + 4) * 128 + nn]); o1.y = f2bf(W[(kc + 5) * 128 + nn]);
        o1.z = f2bf(W[(kc + 6) * 128 + nn]); o1.w = f2bf(W[(kc + 7) * 128 + nn]);
        *(ushort4*)(Wt + nn * 128 + kc) = o0;
        *(ushort4*)(Wt + nn * 128 + kc + 4) = o1;
    }
}

__device__ inline void dev_hist(int b, const Params& p, unsigned int* hist) {
    for (int i = threadIdx.x; i < p.C; i += 256) hist[i] = 0;
    __syncthreads();
    const int base = b * EPB + threadIdx.x;
#pragma unroll
    for (int k = 0; k < EPB / 256; ++k) {
        int e = base + k * 256;
        if (e < p.E) atomicAdd(&hist[((unsigned)p.ei[p.E + e]) >> 7], 1u);
    }
    __syncthreads();
    for (int i = threadIdx.x; i < p.C; i += 256) p.bh[(size_t)b * p.C + i] = hist[i];
}

__device__ inline void dev_scanA(int blk, const Params& p, int* tmp) {
    const int tid = threadIdx.x;
    const int i = blk * 256 + tid;
    int v = 0;
    if (i < p.total) {
        int c = i / p.B1n;
        int b = i - c * p.B1n;
        v = (int)p.bh[(size_t)b * p.C + c];
    }
    tmp[tid] = v;
    __syncthreads();
    for (int off = 1; off < 256; off <<= 1) {
        int t = (tid >= off) ? tmp[tid - off] : 0;
        __syncthreads();
        tmp[tid] += t;
        __syncthreads();
    }
    if (i < p.total) p.ebase[i] = tmp[tid] - v;    // block-local exclusive prefix
    if (tid == 255) p.bsums[blk] = tmp[255];
}

// block-local exclusive prefix of bsums[0..sb) into LDS (requires sb <= 256; 225 here)
__device__ inline void block_pref(const Params& p, int* spref) {
    const int tid = threadIdx.x;
    int v = (tid < p.sb) ? p.bsums[tid] : 0;
    spref[tid] = v;
    __syncthreads();
    for (int off = 1; off < 256; off <<= 1) {
        int t = (tid >= off) ? spref[tid - off] : 0;
        __syncthreads();
        spref[tid] += t;
        __syncthreads();
    }
    int incl = spref[tid];
    __syncthreads();
    spref[tid] = incl - v;   // exclusive
    __syncthreads();
}

__device__ inline void dev_scat(int b, const Params& p, unsigned int* cur, const int* spref) {
    for (int i = threadIdx.x; i < p.C; i += 256) cur[i] = 0;
    __syncthreads();
    const int base = b * EPB + threadIdx.x;
#pragma unroll
    for (int k = 0; k < EPB / 256; ++k) {
        int e = base + k * 256;
        if (e < p.E) {
            int s = p.ei[e];
            unsigned d = (unsigned)p.ei[p.E + e];
            float w = p.ew[e];
            int c = d >> 7;
            unsigned r = atomicAdd(&cur[c], 1u);
            int idx = c * p.B1n + b;
            int pos = p.ebase[idx] + spref[idx >> 8] + (int)r;
            p.brec[pos] = make_int2((int)((d << 16) | (unsigned)s), __float_as_int(w));
        }
    }
}

__device__ inline void dev_cbuild(int c, const Params& p, unsigned int* a, const int* spref) {
    unsigned int* hcnt = a;
    unsigned int* hdeg = a + CSZ;
    unsigned int* lsc  = a + 2 * CSZ;
    unsigned int* curs = a + 3 * CSZ;
    const int tid = threadIdx.x;
    const int i0 = c * p.B1n;
    const int cs = p.ebase[i0] + spref[i0 >> 8];
    int ce;
    if (c + 1 < p.C) {
        const int i1 = (c + 1) * p.B1n;
        ce = p.ebase[i1] + spref[i1 >> 8];
    } else {
        ce = p.E;
    }
    if (tid < CSZ) { hcnt[tid] = 0; hdeg[tid] = 0; }
    __syncthreads();
    for (int i = cs + tid; i < ce; i += 256) {
        int2 r = p.brec[i];
        int local = (int)(((unsigned)r.x) >> 16) & (CSZ - 1);
        atomicAdd(&hcnt[local], 1u);
        atomicAdd(&hdeg[local], (unsigned)(__int_as_float(r.y) * 16777216.0f));
    }
    __syncthreads();
    if (tid < CSZ) lsc[tid] = hcnt[tid];
    __syncthreads();
    for (int off = 1; off < CSZ; off <<= 1) {
        unsigned t = (tid < CSZ && tid >= off) ? lsc[tid - off] : 0u;
        __syncthreads();
        if (tid < CSZ) lsc[tid] += t;
        __syncthreads();
    }
    if (tid < CSZ) {
        unsigned excl = lsc[tid] - hcnt[tid];
        curs[tid] = excl;
        int node = c * CSZ + tid;
        if (node < p.N) {
            p.rowstart[node] = cs + (int)excl;
            p.cnt[node] = (int)hcnt[tid];
            float deg = 1.0f + (float)hdeg[tid] * (1.0f / 16777216.0f);
            p.dinv[node] = rsqrtf(deg);
        }
    }
    __syncthreads();
    for (int i = cs + tid; i < ce; i += 256) {
        int2 r = p.brec[i];
        int local = (int)(((unsigned)r.x) >> 16) & (CSZ - 1);
        unsigned rk = atomicAdd(&curs[local], 1u);
        p.erec[cs + (int)rk] = make_int2(r.x & 0xFFFF, r.y);   // (src, ew)
    }
}

// ---------------- MFMA GEMM body (R0-verified, verbatim): GEMM1 ----------------
template <bool IN_BF16>
__device__ inline void mfma_body(unsigned short* sE,
                                 const void* __restrict__ Xv,
                                 const unsigned short* __restrict__ Wt,
                                 unsigned short* __restrict__ H, int n, int blk) {
    const int tid = threadIdx.x;
    const int row0 = blk * 64;
    const int lane = tid & 63;
    const int wv = tid >> 6;
    const int qm = lane & 15;
    const int quad = lane >> 4;

    const int arow = row0 + wv * 16 + qm;
    const int ar = (arow < n) ? arow : (n - 1);

    f32x4 acc[8];
#pragma unroll
    for (int i = 0; i < 8; ++i) acc[i] = (f32x4){0.f, 0.f, 0.f, 0.f};

#pragma unroll
    for (int kb = 0; kb < 4; ++kb) {
        const int koff = kb * 32 + quad * 8;
        bf16x8 a;
        if (IN_BF16) {
            a = *(const bf16x8*)((const unsigned short*)Xv + (size_t)ar * 128 + koff);
        } else {
            const float* Xf = (const float*)Xv + (size_t)ar * 128 + koff;
            float4 v0 = *(const float4*)(Xf);
            float4 v1 = *(const float4*)(Xf + 4);
            union { bf16x8 v; ushort4 u[2]; } cv;
            cv.u[0].x = f2bf(v0.x); cv.u[0].y = f2bf(v0.y);
            cv.u[0].z = f2bf(v0.z); cv.u[0].w = f2bf(v0.w);
            cv.u[1].x = f2bf(v1.x); cv.u[1].y = f2bf(v1.y);
            cv.u[1].z = f2bf(v1.z); cv.u[1].w = f2bf(v1.w);
            a = cv.v;
        }
#pragma unroll
        for (int n0 = 0; n0 < 8; ++n0) {
            bf16x8 b = *(const bf16x8*)(Wt + (n0 * 16 + qm) * 128 + koff);
            acc[n0] = __builtin_amdgcn_mfma_f32_16x16x32_bf16(a, b, acc[n0], 0, 0, 0);
        }
    }

#pragma unroll
    for (int n0 = 0; n0 < 8; ++n0)
#pragma unroll
        for (int r = 0; r < 4; ++r)
            sE[(wv * 16 + quad * 4 + r) * 136 + n0 * 16 + qm] = f2bf(acc[n0][r]);
    __syncthreads();

    const int row_in = lane >> 2;
    const int c0 = (lane & 3) * 4;
    const int grow = row0 + wv * 16 + row_in;
    if (grow < n) {
#pragma unroll
        for (int j = 0; j < 4; ++j)
            *(int4*)(H + (size_t)grow * 128 + (c0 + j) * 8) =
                *(const int4*)(&sE[(wv * 16 + row_in) * 136 + (c0 + j) * 8]);
    }
}

// ---------------- gather layer-1, 16 lanes/node, int4 row loads (R8-verified, 4-deep) ----------------
__device__ inline void gather1_node16(const Params& p, unsigned short* dst, int node, int lane) {
    const int4* __restrict__ H16 = (const int4*)p.Hbuf;   // 16 int4 per 128-col bf16 row
    union U8 { int4 v; unsigned short u[8]; };
    if (node < p.N) {
        const int start = p.rowstart[node];
        const int m = p.cnt[node];
        const float di = p.dinv[node];
        U8 s; s.v = H16[(size_t)node * 16 + lane];
        float acc[8];
#pragma unroll
        for (int q = 0; q < 8; ++q) acc[q] = di * bf2f(s.u[q]);

        const int2* __restrict__ er = p.erec + start;
        int j = 0;
        for (; j + 4 <= m; j += 4) {
            int2 e0 = er[j], e1 = er[j + 1], e2 = er[j + 2], e3 = er[j + 3];
            U8 v0, v1, v2, v3;
            v0.v = H16[(size_t)e0.x * 16 + lane];
            v1.v = H16[(size_t)e1.x * 16 + lane];
            v2.v = H16[(size_t)e2.x * 16 + lane];
            v3.v = H16[(size_t)e3.x * 16 + lane];
            float w0 = p.dinv[e0.x] * __int_as_float(e0.y);
            float w1 = p.dinv[e1.x] * __int_as_float(e1.y);
            float w2 = p.dinv[e2.x] * __int_as_float(e2.y);
            float w3 = p.dinv[e3.x] * __int_as_float(e3.y);
#pragma unroll
            for (int q = 0; q < 8; ++q)
                acc[q] += w0 * bf2f(v0.u[q]) + w1 * bf2f(v1.u[q]) +
                          w2 * bf2f(v2.u[q]) + w3 * bf2f(v3.u[q]);
        }
        for (; j < m; ++j) {
            int2 e0 = er[j];
            U8 v0; v0.v = H16[(size_t)e0.x * 16 + lane];
            float w0 = p.dinv[e0.x] * __int_as_float(e0.y);
#pragma unroll
            for (int q = 0; q < 8; ++q) acc[q] += w0 * bf2f(v0.u[q]);
        }
        const float4 b0 = *(const float4*)(p.b1 + lane * 8);
        const float4 b1v = *(const float4*)(p.b1 + lane * 8 + 4);
        const float bb[8] = {b0.x, b0.y, b0.z, b0.w, b1v.x, b1v.y, b1v.z, b1v.w};
        U8 o;
#pragma unroll
        for (int q = 0; q < 8; ++q) o.u[q] = f2bf(fmaxf(bb[q] + di * acc[q], 0.f));
        *(int4*)dst = o.v;
    } else {
        *(int4*)dst = (int4){0, 0, 0, 0};
    }
}

// ---------------- gather layer 2, 16 lanes/node, int4 row loads (R8-verified, 4-deep) ----------------
__device__ inline void gather2_body16(const Params& p, const int4* __restrict__ H16,
                                      const float* __restrict__ bias,
                                      float4* __restrict__ OUT, int g) {
    const int lane = threadIdx.x & 15;
    const int node = g * 16 + (threadIdx.x >> 4);
    if (node >= p.N) return;
    const int start = p.rowstart[node];
    const int m = p.cnt[node];
    const float di = p.dinv[node];

    union U8 { int4 v; unsigned short u[8]; };
    U8 s; s.v = H16[(size_t)node * 16 + lane];
    float acc[8];
#pragma unroll
    for (int q = 0; q < 8; ++q) acc[q] = bf2f(s.u[q]);

    const int2* __restrict__ er = p.erec + start;
    int j = 0;
    for (; j + 4 <= m; j += 4) {
        int2 e0 = er[j], e1 = er[j + 1], e2 = er[j + 2], e3 = er[j + 3];
        U8 v0, v1, v2, v3;
        v0.v = H16[(size_t)e0.x * 16 + lane];
        v1.v = H16[(size_t)e1.x * 16 + lane];
        v2.v = H16[(size_t)e2.x * 16 + lane];
        v3.v = H16[(size_t)e3.x * 16 + lane];
        float w0 = __int_as_float(e0.y), w1 = __int_as_float(e1.y);
        float w2 = __int_as_float(e2.y), w3 = __int_as_float(e3.y);
#pragma unroll
        for (int q = 0; q < 8; ++q)
            acc[q] += w0 * bf2f(v0.u[q]) + w1 * bf2f(v1.u[q]) +
                      w2 * bf2f(v2.u[q]) + w3 * bf2f(v3.u[q]);
    }
    for (; j < m; ++j) {
        int2 e0 = er[j];
        U8 v0; v0.v = H16[(size_t)e0.x * 16 + lane];
        float w0 = __int_as_float(e0.y);
#pragma unroll
        for (int q = 0; q < 8; ++q) acc[q] += w0 * bf2f(v0.u[q]);
    }

    const float4 b0 = *(const float4*)(bias + lane * 8);
    const float4 b1v = *(const float4*)(bias + lane * 8 + 4);
    float4 f0, f1;
    f0.x = b0.x + di * acc[0]; f0.y = b0.y + di * acc[1];
    f0.z = b0.z + di * acc[2]; f0.w = b0.w + di * acc[3];
    f1.x = b1v.x + di * acc[4]; f1.y = b1v.y + di * acc[5];
    f1.z = b1v.z + di * acc[6]; f1.w = b1v.w + di * acc[7];
    OUT[(size_t)node * 32 + lane * 2] = f0;
    OUT[(size_t)node * 32 + lane * 2 + 1] = f1;
}

// ================= 6-kernel pipeline with GEMM1 spread across CSR launches =================
__global__ __launch_bounds__(256, 4) void k_f0(Params p) {   // prep + hist
    __shared__ __align__(16) unsigned int hist[512];
    if (blockIdx.x < 2) dev_prep(blockIdx.x, p);
    else dev_hist(blockIdx.x - 2, p, hist);
}
// scanA + GEMM1 chunk A (blocks [0, g1))
__global__ __launch_bounds__(256, 4) void k_f1(Params p) {
    __shared__ __align__(16) char arena[64 * 136 * 2];
    if ((int)blockIdx.x < p.sb) dev_scanA(blockIdx.x, p, (int*)arena);
    else mfma_body<false>((unsigned short*)arena, (const void*)p.x, p.Wt1, p.Hbuf, p.N, blockIdx.x - p.sb);
}
// scat + GEMM1 chunk B (blocks [g1, g1+g2))
__global__ __launch_bounds__(256, 4) void k_f3(Params p) {
    __shared__ __align__(16) char arena[64 * 136 * 2];
    if ((int)blockIdx.x < p.B1n) {
        unsigned int* cur = (unsigned int*)arena;          // 2048 B
        int* spref = (int*)(arena + 2048);                 // 1024 B
        block_pref(p, spref);
        dev_scat(blockIdx.x, p, cur, spref);
    } else {
        mfma_body<false>((unsigned short*)arena, (const void*)p.x, p.Wt1, p.Hbuf, p.N,
                         p.g1 + (int)blockIdx.x - p.B1n);
    }
}
// cbuild + GEMM1 chunk C (blocks [g1+g2, gb))
__global__ __launch_bounds__(256, 4) void k_f4(Params p) {
    __shared__ __align__(16) char arena[64 * 136 * 2];
    if ((int)blockIdx.x < p.C) {
        unsigned int* a = (unsigned int*)arena;            // 2048 B
        int* spref = (int*)(arena + 2048);                 // 1024 B
        block_pref(p, spref);
        dev_cbuild(blockIdx.x, p, a, spref);
    } else {
        mfma_body<false>((unsigned short*)arena, (const void*)p.x, p.Wt1, p.Hbuf, p.N,
                         p.g1 + p.g2 + (int)blockIdx.x - p.C);
    }
}
// fused gather1 + GEMM2, 32-row tile, 16-lane 4-deep gather + dinv-fold epilogue (R8-verified)
__global__ __launch_bounds__(256, 4) void k_g5(Params p) {
    __shared__ __align__(16) unsigned short sA[32 * 136];
    __shared__ __align__(16) unsigned short sE[32 * 136];
    const int row0 = blockIdx.x * 32;
    const int tid = threadIdx.x;

    // gather 32 nodes: 16 lanes/node, 16 nodes/pass, 2 passes
    const int lane16 = tid & 15;
    const int grp16 = tid >> 4;   // 0..15
#pragma unroll
    for (int pass = 0; pass < 2; ++pass) {
        const int local = pass * 16 + grp16;
        gather1_node16(p, sA + local * 136 + lane16 * 8, row0 + local, lane16);
    }
    __syncthreads();

    const int lane = tid & 63;
    const int wv = tid >> 6;        // 0..3
    const int qm = lane & 15;
    const int quad = lane >> 4;
    const int rh = wv & 1;          // row half (16 rows)
    const int ch = wv >> 1;         // col half (64 cols)

    f32x4 acc[4];
#pragma unroll
    for (int i = 0; i < 4; ++i) acc[i] = (f32x4){0.f, 0.f, 0.f, 0.f};

#pragma unroll
    for (int kb = 0; kb < 4; ++kb) {
        const int koff = kb * 32 + quad * 8;
        bf16x8 a = *(const bf16x8*)(sA + (rh * 16 + qm) * 136 + koff);
#pragma unroll
        for (int n0 = 0; n0 < 4; ++n0) {
            bf16x8 b = *(const bf16x8*)(p.Wt2 + ((ch * 4 + n0) * 16 + qm) * 128 + koff);
            acc[n0] = __builtin_amdgcn_mfma_f32_16x16x32_bf16(a, b, acc[n0], 0, 0, 0);
        }
    }

    // per-C-row dinv (fold into H2s, fp32 before the single bf16 rounding)
    const int crow = rh * 16 + quad * 4;
    float di[4];
#pragma unroll
    for (int r = 0; r < 4; ++r) {
        int rr = row0 + crow + r;
        int rc = (rr < p.N) ? rr : (p.N - 1);
        di[r] = p.dinv[rc];
    }

#pragma unroll
    for (int n0 = 0; n0 < 4; ++n0)
#pragma unroll
        for (int r = 0; r < 4; ++r)
            sE[(crow + r) * 136 + ch * 64 + n0 * 16 + qm] = f2bf(acc[n0][r] * di[r]);
    __syncthreads();

    // write 32 rows x 128 cols: each thread 2 int4 chunks
    const int row_in = tid >> 3;          // 0..31
    const int c0 = (tid & 7) * 2;         // int4-chunk pair
    const int grow = row0 + row_in;
    if (grow < p.N) {
        *(int4*)(p.Abuf + (size_t)grow * 128 + (c0 + 0) * 8) =
            *(const int4*)(&sE[row_in * 136 + (c0 + 0) * 8]);
        *(int4*)(p.Abuf + (size_t)grow * 128 + (c0 + 1) * 8) =
            *(const int4*)(&sE[row_in * 136 + (c0 + 1) * 8]);
    }
}
__global__ __launch_bounds__(256) void k_g6(Params p) {      // gather2 -> out fp32
    gather2_body16(p, (const int4*)p.Abuf, p.b2, (float4*)p.out, blockIdx.x);
}

extern "C" void kernel_launch(void* const* d_in, const int* in_sizes, int n_in,
                              void* d_out, int out_size, void* d_ws, size_t ws_size,
                              hipStream_t stream) {
    Params p;
    p.x  = (const float*)d_in[0];
    p.ei = (const int*)d_in[1];
    p.ew = (const float*)d_in[2];
    p.W1 = (const float*)d_in[3];
    p.b1 = (const float*)d_in[4];
    p.W2 = (const float*)d_in[5];
    p.b2 = (const float*)d_in[6];
    p.out = (float*)d_out;

    p.N = in_sizes[0] / D;
    p.E = in_sizes[2];
    p.C = (p.N + CSZ - 1) / CSZ;
    p.B1n = (p.E + EPB - 1) / EPB;
    p.total = p.C * p.B1n;
    p.sb = (p.total + 255) / 256;     // must be <= 256 for block_pref (225 here)
    p.gb = (p.N + 63) / 64;
    p.gb2 = (p.N + 31) / 32;
    p.hb16 = (p.N + 15) / 16;
    // GEMM1 block split across the three CSR launches (weighted by stage duration)
    p.g1 = p.gb / 8;                  // with scanA (short stage)
    p.g2 = (3 * p.gb) / 8;            // with scat
    p.g3 = p.gb - p.g1 - p.g2;        // with cbuild (longest stage)

    char* w = (char*)d_ws;
    auto alloc = [&](size_t bytes) {
        void* r = (void*)w;
        w += (bytes + 255) & ~(size_t)255;
        return r;
    };
    p.bh       = (unsigned int*)alloc((size_t)p.total * 4);
    p.ebase    = (int*)alloc((size_t)p.total * 4);
    p.bsums    = (int*)alloc((size_t)(p.sb + 1) * 4);
    p.dinv     = (float*)alloc((size_t)p.N * 4);
    p.cnt      = (int*)alloc((size_t)p.N * 4);
    p.rowstart = (int*)alloc((size_t)p.N * 4);
    p.brec     = (int2*)alloc((size_t)p.E * 8);
    p.erec     = (int2*)alloc((size_t)p.E * 8);
    p.Hbuf     = (unsigned short*)alloc((size_t)p.N * D * 2);
    p.Abuf     = (unsigned short*)alloc((size_t)p.N * D * 2);
    p.Wt1      = (unsigned short*)alloc(128 * 128 * 2);
    p.Wt2      = (unsigned short*)alloc(128 * 128 * 2);

    k_f0<<<2 + p.B1n, 256, 0, stream>>>(p);
    k_f1<<<p.sb + p.g1, 256, 0, stream>>>(p);
    k_f3<<<p.B1n + p.g2, 256, 0, stream>>>(p);
    k_f4<<<p.C + p.g3, 256, 0, stream>>>(p);
    k_g5<<<p.gb2, 256, 0, stream>>>(p);
    k_g6<<<p.hb16, 256, 0, stream>>>(p);
}